// Round 14
// baseline (353.957 us; speedup 1.0000x reference)
//
#include <hip/hip_runtime.h>
#include <hip/hip_bf16.h>

#define F_IN 128
#define F_HID 64
#define F_OUT 128
#define BSH 9                 // 512 nodes per bucket
#define BS  (1 << BSH)
#define MAXNB 256

__device__ __forceinline__ int clampi(int v, int lo, int hi) {
    return v < lo ? lo : (v > hi ? hi : v);
}

// RNE float->bf16 (explicit, no dependence on hip_bf16 ABI)
__device__ __forceinline__ unsigned short f2bf(float f) {
    unsigned int u = __float_as_uint(f);
    u = (u + 0x7FFFu + ((u >> 16) & 1u)) >> 16;
    return (unsigned short)u;
}
__device__ __forceinline__ float bf2f(unsigned short s) {
    return __uint_as_float(((unsigned int)s) << 16);
}

// ---------------- B1: coarse bucket histogram ----------------
__global__ void bhist_kernel(const int* __restrict__ dst, int* __restrict__ bhist,
                             int E, int Nn, int NB) {
    __shared__ int lh[MAXNB];
    for (int i = threadIdx.x; i < NB; i += 256) lh[i] = 0;
    __syncthreads();
    int chunk = (E + gridDim.x - 1) / gridDim.x;
    int base = blockIdx.x * chunk;
    int end = base + chunk; if (end > E) end = E;
    for (int i = base + threadIdx.x; i < end; i += 256) {
        int d = clampi(dst[i], 0, Nn - 1);
        atomicAdd(&lh[d >> BSH], 1);
    }
    __syncthreads();
    for (int i = threadIdx.x; i < NB; i += 256)
        if (lh[i]) atomicAdd(&bhist[i], lh[i]);
}

// ---------------- bplace BODY (device fn; LDS passed in; r7-r13 proven) ----------------
__device__ void bplace_body(int* lh, int* gb, int* bbuf, int lb, int NPL,
                            const int* __restrict__ src, const int* __restrict__ dst,
                            const int* __restrict__ bhist, int* __restrict__ bbase,
                            int* __restrict__ bcur, int* __restrict__ staging,
                            int E, int Nn, int NB) {
    int t = threadIdx.x;                         // blockDim = 256 = MAXNB
    int v = (t < NB) ? bhist[t] : 0;
    bbuf[t] = v;
    __syncthreads();
    for (int dd = 1; dd < MAXNB; dd <<= 1) {
        int x = (t >= dd) ? bbuf[t - dd] : 0;
        __syncthreads();
        bbuf[t] += x;
        __syncthreads();
    }
    int excl = bbuf[t] - v;
    __syncthreads();
    bbuf[t] = excl;
    if (lb == 0 && t < NB) bbase[t] = excl;
    for (int i = t; i < NB; i += 256) lh[i] = 0;
    __syncthreads();

    int chunk = (E + NPL - 1) / NPL;
    int base = lb * chunk;
    int end = base + chunk; if (end > E) end = E;
    for (int i = base + t; i < end; i += 256) {
        int d = clampi(dst[i], 0, Nn - 1);
        atomicAdd(&lh[d >> BSH], 1);
    }
    __syncthreads();
    for (int i = t; i < NB; i += 256) {
        int c = lh[i];
        gb[i] = (c > 0) ? bbuf[i] + atomicAdd(&bcur[i], c) : 0;
        lh[i] = 0;                               // reuse as local cursor
    }
    __syncthreads();
    for (int i = base + t; i < end; i += 256) {
        int d = clampi(dst[i], 0, Nn - 1);
        int s = clampi(src[i], 0, Nn - 1);
        int b = d >> BSH;
        int p = gb[b] + atomicAdd(&lh[b], 1);    // contiguous run per block*bucket
        staging[p] = (s << BSH) | (d & (BS - 1));
    }
}

// ---------------- bfine BODY (256-thr r8-proven version; LDS passed in) ----------------
__device__ void bfine_body(int* lcnt, int* loff, int* lcur, int* ps, int b,
                           const int* __restrict__ bhist, const int* __restrict__ bbase,
                           const int* __restrict__ staging,
                           int* __restrict__ cnt, int* __restrict__ off,
                           float* __restrict__ nrm, int* __restrict__ csr, int Nn) {
    int t = threadIdx.x;                         // blockDim = 256
    int base  = bbase[b];
    int count = bhist[b];
    int node0 = b << BSH;

    for (int r = t; r < BS; r += 256) lcnt[r] = 0;
    __syncthreads();
    for (int i = t; i < count; i += 256)
        atomicAdd(&lcnt[staging[base + i] & (BS - 1)], 1);
    __syncthreads();

    // exclusive scan of lcnt[512] with 256 threads (pair scan, r8-verified)
    int a0 = lcnt[2 * t], a1 = lcnt[2 * t + 1];
    int pair = a0 + a1;
    ps[t] = pair;
    __syncthreads();
    for (int d = 1; d < 256; d <<= 1) {
        int x = (t >= d) ? ps[t - d] : 0;
        __syncthreads();
        ps[t] += x;
        __syncthreads();
    }
    int excl = ps[t] - pair;
    loff[2 * t]     = excl;
    loff[2 * t + 1] = excl + a0;
    __syncthreads();

    for (int r = t; r < BS; r += 256) {
        int node = node0 + r;
        if (node < Nn) {
            int c = lcnt[r];
            cnt[node] = c;
            off[node] = base + loff[r];
            nrm[node] = rsqrtf((float)c + 1.0f);
        }
        lcur[r] = 0;
    }
    __syncthreads();

    for (int i = t; i < count; i += 256) {
        int v = staging[base + i];
        int r = v & (BS - 1);
        int p = base + loff[r] + atomicAdd(&lcur[r], 1);
        csr[p] = v >> BSH;
    }
}

// ---------------- GEMM BODY (v5 straight kk+=8 loop — PERMANENTLY FROZEN) ----------------
// r12 verdict: ping-pong prefetch state (acc 32 + 64 prefetch VGPR > budget)
// deterministically spills -> GB-scale scratch storm. This body (peak live ~70,
// av/av2 die between j-loops) ran clean r4/r8/r9/r10/r13. DO NOT ADD PREFETCH
// STATE. DO NOT CHANGE GEOMETRY.
template<int K, int N, bool BIAS, bool BF16OUT>
__device__ void gemm_body(float* __restrict__ Ws, int lb,
                          const float* __restrict__ A, const float* __restrict__ B,
                          const float* __restrict__ bias,
                          void* __restrict__ Cv, int M) {
    constexpr int CT = N / 8;
    constexpr int RB = (256 / CT) * 4;

    int tid = threadIdx.x;
    for (int i = tid; i < K * N / 4; i += 256)
        ((float4*)Ws)[i] = ((const float4*)B)[i];
    __syncthreads();

    int ct = tid % CT;
    int rt = tid / CT;
    int row0 = lb * RB + rt * 4;
    int c0 = ct * 8;

    float acc[4][8];
#pragma unroll
    for (int r = 0; r < 4; r++)
#pragma unroll
        for (int c = 0; c < 8; c++) acc[r][c] = 0.f;

    for (int kk = 0; kk < K; kk += 8) {
        float4 av[4], av2[4];
#pragma unroll
        for (int r = 0; r < 4; r++) {
            int row = row0 + r;
            if (row < M) {
                av[r]  = *(const float4*)(A + (size_t)row * K + kk);
                av2[r] = *(const float4*)(A + (size_t)row * K + kk + 4);
            } else {
                av[r]  = make_float4(0.f, 0.f, 0.f, 0.f);
                av2[r] = make_float4(0.f, 0.f, 0.f, 0.f);
            }
        }
#pragma unroll
        for (int j = 0; j < 4; j++) {
            const float* wrow = Ws + (kk + j) * N + c0;
            float4 w0 = *(const float4*)(wrow);
            float4 w1 = *(const float4*)(wrow + 4);
            float wj[8] = {w0.x, w0.y, w0.z, w0.w, w1.x, w1.y, w1.z, w1.w};
#pragma unroll
            for (int r = 0; r < 4; r++) {
                float a = (j == 0) ? av[r].x : (j == 1) ? av[r].y : (j == 2) ? av[r].z : av[r].w;
#pragma unroll
                for (int c = 0; c < 8; c++)
                    acc[r][c] = fmaf(a, wj[c], acc[r][c]);
            }
        }
#pragma unroll
        for (int j = 0; j < 4; j++) {
            const float* wrow = Ws + (kk + 4 + j) * N + c0;
            float4 w0 = *(const float4*)(wrow);
            float4 w1 = *(const float4*)(wrow + 4);
            float wj[8] = {w0.x, w0.y, w0.z, w0.w, w1.x, w1.y, w1.z, w1.w};
#pragma unroll
            for (int r = 0; r < 4; r++) {
                float a = (j == 0) ? av2[r].x : (j == 1) ? av2[r].y : (j == 2) ? av2[r].z : av2[r].w;
#pragma unroll
                for (int c = 0; c < 8; c++)
                    acc[r][c] = fmaf(a, wj[c], acc[r][c]);
            }
        }
    }

    float bcol[8];
    if (BIAS) {
        float4 bb0 = *(const float4*)(bias + c0);
        float4 bb1 = *(const float4*)(bias + c0 + 4);
        bcol[0]=bb0.x; bcol[1]=bb0.y; bcol[2]=bb0.z; bcol[3]=bb0.w;
        bcol[4]=bb1.x; bcol[5]=bb1.y; bcol[6]=bb1.z; bcol[7]=bb1.w;
    }

#pragma unroll
    for (int r = 0; r < 4; r++) {
        int row = row0 + r;
        if (row >= M) continue;
        float o[8];
#pragma unroll
        for (int c = 0; c < 8; c++) {
            float v = acc[r][c];
            if (BIAS) v += bcol[c];
            o[c] = v;
        }
        if (BF16OUT) {
            unsigned int pk0 = (unsigned int)f2bf(o[0]) | ((unsigned int)f2bf(o[1]) << 16);
            unsigned int pk1 = (unsigned int)f2bf(o[2]) | ((unsigned int)f2bf(o[3]) << 16);
            unsigned int pk2 = (unsigned int)f2bf(o[4]) | ((unsigned int)f2bf(o[5]) << 16);
            unsigned int pk3 = (unsigned int)f2bf(o[6]) | ((unsigned int)f2bf(o[7]) << 16);
            uint4 pk; pk.x = pk0; pk.y = pk1; pk.z = pk2; pk.w = pk3;
            *(uint4*)((unsigned short*)Cv + (size_t)row * N + c0) = pk;
        } else {
            float4 o0, o1;
            o0.x = o[0]; o0.y = o[1]; o0.z = o[2]; o0.w = o[3];
            o1.x = o[4]; o1.y = o[5]; o1.z = o[6]; o1.w = o[7];
            float* crow = (float*)Cv + (size_t)row * N + c0;
            *(float4*)(crow) = o0;
            *(float4*)(crow + 4) = o1;
        }
    }
}

// ---------------- standalone GEMM kernel (layer 2) ----------------
template<int K, int N, bool BIAS, bool BF16OUT>
__global__ void gemm_tiled(const float* __restrict__ A, const float* __restrict__ B,
                           const float* __restrict__ bias,
                           void* __restrict__ Cv, int M) {
    __shared__ float Ws[K * N];
    gemm_body<K, N, BIAS, BF16OUT>(Ws, blockIdx.x, A, B, bias, Cv, M);
}

// ---------------- FUSED K1: gemm1 rows [0, NG*128) || bplace ----------------
// r9/r10/r13-verified pattern: CSR work hides inside gemm1's latency stalls.
__global__ void gemm1a_bplace_kernel(const float* __restrict__ x, const float* __restrict__ W1,
                                     unsigned short* __restrict__ h1, int M, int NG,
                                     const int* __restrict__ src, const int* __restrict__ dst,
                                     const int* __restrict__ bhist, int* __restrict__ bbase,
                                     int* __restrict__ bcur, int* __restrict__ staging,
                                     int E, int Nn, int NB, int NPL) {
    __shared__ union SmA {
        float ws[F_IN * F_HID];                         // 32 KB
        struct { int lh[MAXNB]; int gb[MAXNB]; int bb[MAXNB]; } pl;  // 3 KB
    } sm;
    if ((int)blockIdx.x < NG) {
        gemm_body<F_IN, F_HID, false, true>(sm.ws, blockIdx.x, x, W1, nullptr, h1, M);
    } else {
        bplace_body(sm.pl.lh, sm.pl.gb, sm.pl.bb, blockIdx.x - NG, NPL,
                    src, dst, bhist, bbase, bcur, staging, E, Nn, NB);
    }
}

// ---------------- FUSED K2: gemm1 rows [ROW0*128, ...) || bfine ----------------
// bfine depends on bplace (K1) — satisfied by the K1->K2 stream boundary.
// gemm1's remaining row range is independent of the CSR chain entirely.
__global__ void gemm1b_bfine_kernel(const float* __restrict__ x, const float* __restrict__ W1,
                                    unsigned short* __restrict__ h1, int M, int ROW0, int NG2,
                                    const int* __restrict__ bhist, const int* __restrict__ bbase,
                                    const int* __restrict__ staging,
                                    int* __restrict__ cnt, int* __restrict__ off,
                                    float* __restrict__ nrm, int* __restrict__ csr, int Nn) {
    __shared__ union SmB {
        float ws[F_IN * F_HID];                         // 32 KB
        struct { int lcnt[BS]; int loff[BS]; int lcur[BS]; int ps[256]; } f;  // 7 KB
    } sm;
    if ((int)blockIdx.x < NG2) {
        gemm_body<F_IN, F_HID, false, true>(sm.ws, blockIdx.x + ROW0, x, W1, nullptr, h1, M);
    } else {
        bfine_body(sm.f.lcnt, sm.f.loff, sm.f.lcur, sm.f.ps, blockIdx.x - NG2,
                   bhist, bbase, staging, cnt, off, nrm, csr, Nn);
    }
}

// ---------------- gather1 (CONV): per-edge norm fma (h1 is UNSCALED bf16) ----------------
__global__ void gather64_conv_kernel(const unsigned short* __restrict__ h,
                                     const float* __restrict__ norm,
                                     const int* __restrict__ off, const int* __restrict__ cnt,
                                     const int* __restrict__ csr_src,
                                     const float* __restrict__ bias,
                                     unsigned short* __restrict__ outp, int Nn, int E) {
    int wave = (blockIdx.x * blockDim.x + threadIdx.x) >> 6;
    int lane = threadIdx.x & 63;
    int node = __builtin_amdgcn_readfirstlane(wave);
    if (node >= Nn) return;

    int o0 = __builtin_amdgcn_readfirstlane(off[node]);
    int c  = __builtin_amdgcn_readfirstlane(cnt[node]);
    if (c < 0) c = 0;
    if (o0 < 0) o0 = 0;
    if (o0 + c > E) c = E - o0;

    const int* ce = csr_src + o0;
    float sum = 0.0f;
    int e = 0;
    for (; e + 16 <= c; e += 16) {
        int si[16];
        float nw[16];
        unsigned short v[16];
#pragma unroll
        for (int u = 0; u < 16; u++) si[u] = clampi(ce[e + u], 0, Nn - 1);
#pragma unroll
        for (int u = 0; u < 16; u++) nw[u] = norm[si[u]];
#pragma unroll
        for (int u = 0; u < 16; u++) v[u] = h[(size_t)si[u] * 64 + lane];
#pragma unroll
        for (int u = 0; u < 16; u++) sum = fmaf(nw[u], bf2f(v[u]), sum);
    }
    for (; e + 8 <= c; e += 8) {
        int si[8];
        float nw[8];
        unsigned short v[8];
#pragma unroll
        for (int u = 0; u < 8; u++) si[u] = clampi(ce[e + u], 0, Nn - 1);
#pragma unroll
        for (int u = 0; u < 8; u++) nw[u] = norm[si[u]];
#pragma unroll
        for (int u = 0; u < 8; u++) v[u] = h[(size_t)si[u] * 64 + lane];
#pragma unroll
        for (int u = 0; u < 8; u++) sum = fmaf(nw[u], bf2f(v[u]), sum);
    }
    for (; e + 4 <= c; e += 4) {
        int si[4];
        float nw[4];
        unsigned short v[4];
#pragma unroll
        for (int u = 0; u < 4; u++) si[u] = clampi(ce[e + u], 0, Nn - 1);
#pragma unroll
        for (int u = 0; u < 4; u++) nw[u] = norm[si[u]];
#pragma unroll
        for (int u = 0; u < 4; u++) v[u] = h[(size_t)si[u] * 64 + lane];
#pragma unroll
        for (int u = 0; u < 4; u++) sum = fmaf(nw[u], bf2f(v[u]), sum);
    }
    for (; e < c; e++) {
        int s = clampi(ce[e], 0, Nn - 1);
        sum = fmaf(norm[s], bf2f(h[(size_t)s * 64 + lane]), sum);
    }
    float self = bf2f(h[(size_t)node * 64 + lane]);
    float nv = norm[node];
    float r = nv * (sum + nv * self);
    r = nv * fmaxf(r + bias[lane], 0.0f);
    outp[(size_t)node * 64 + lane] = f2bf(r);
}

// ---------------- gather2 (plain): p is pre-scaled bf16; q = nv*(sum+self) f32 ----------------
__global__ void gather64_plain_kernel(const unsigned short* __restrict__ h,
                                      const float* __restrict__ norm,
                                      const int* __restrict__ off, const int* __restrict__ cnt,
                                      const int* __restrict__ csr_src,
                                      float* __restrict__ outq, int Nn, int E) {
    int wave = (blockIdx.x * blockDim.x + threadIdx.x) >> 6;
    int lane = threadIdx.x & 63;
    int node = __builtin_amdgcn_readfirstlane(wave);
    if (node >= Nn) return;

    int o0 = __builtin_amdgcn_readfirstlane(off[node]);
    int c  = __builtin_amdgcn_readfirstlane(cnt[node]);
    if (c < 0) c = 0;
    if (o0 < 0) o0 = 0;
    if (o0 + c > E) c = E - o0;

    const int* ce = csr_src + o0;
    float sum = 0.0f;
    int e = 0;
    for (; e + 16 <= c; e += 16) {
        int si[16];
        unsigned short v[16];
#pragma unroll
        for (int u = 0; u < 16; u++) si[u] = clampi(ce[e + u], 0, Nn - 1);
#pragma unroll
        for (int u = 0; u < 16; u++) v[u] = h[(size_t)si[u] * 64 + lane];
#pragma unroll
        for (int u = 0; u < 16; u++) sum += bf2f(v[u]);
    }
    for (; e + 8 <= c; e += 8) {
        int si[8];
        unsigned short v[8];
#pragma unroll
        for (int u = 0; u < 8; u++) si[u] = clampi(ce[e + u], 0, Nn - 1);
#pragma unroll
        for (int u = 0; u < 8; u++) v[u] = h[(size_t)si[u] * 64 + lane];
#pragma unroll
        for (int u = 0; u < 8; u++) sum += bf2f(v[u]);
    }
    for (; e + 4 <= c; e += 4) {
        int si[4];
        unsigned short v[4];
#pragma unroll
        for (int u = 0; u < 4; u++) si[u] = clampi(ce[e + u], 0, Nn - 1);
#pragma unroll
        for (int u = 0; u < 4; u++) v[u] = h[(size_t)si[u] * 64 + lane];
#pragma unroll
        for (int u = 0; u < 4; u++) sum += bf2f(v[u]);
    }
    for (; e < c; e++) {
        int s = clampi(ce[e], 0, Nn - 1);
        sum += bf2f(h[(size_t)s * 64 + lane]);
    }
    float self = bf2f(h[(size_t)node * 64 + lane]);
    float nv = norm[node];
    outq[(size_t)node * 64 + lane] = nv * (sum + self);
}

extern "C" void kernel_launch(void* const* d_in, const int* in_sizes, int n_in,
                              void* d_out, int out_size, void* d_ws, size_t ws_size,
                              hipStream_t stream) {
    if (n_in < 6) return;
    const float* x   = (const float*)d_in[0];   // [N,128] f32
    const int*   ei  = (const int*)d_in[1];     // [2,E] int32
    const float* W1  = (const float*)d_in[2];   // [128,64] f32
    const float* b1  = (const float*)d_in[3];   // [64] f32
    const float* W2  = (const float*)d_in[4];   // [64,128] f32
    const float* b2  = (const float*)d_in[5];   // [128] f32
    float*       out = (float*)d_out;           // [N,128] f32

    int Nn = in_sizes[0] / F_IN;
    int E  = in_sizes[1] / 2;
    const int* src = ei;
    const int* dst = ei + E;

    int NB = (Nn + BS - 1) >> BSH;              // 196 for 100k
    if (NB > MAXNB) return;
    if (Nn > (1 << (31 - BSH))) return;

    // ---- workspace layout (~40 MB), guarded ----
    size_t o = 0;
    auto alloc = [&](size_t bytes) { size_t cur = o; o += (bytes + 255) & ~(size_t)255; return cur; };
    size_t o_cnt   = alloc((size_t)Nn * 4);
    size_t o_off   = alloc((size_t)Nn * 4);
    size_t o_nrm   = alloc((size_t)Nn * 4);
    size_t o_csr   = alloc((size_t)E * 4);
    size_t o_stg   = alloc((size_t)E * 4);
    size_t o_bh    = alloc(MAXNB * 4);          // bh, bb, bc contiguous (3 KB)
    size_t o_bb    = alloc(MAXNB * 4);
    size_t o_bc    = alloc(MAXNB * 4);
    size_t o_h     = alloc((size_t)Nn * F_HID * 4);   // q (f32) overlays h1 (bf16)
    if (o > ws_size) return;

    char* ws = (char*)d_ws;
    int*   cnt   = (int*)(ws + o_cnt);
    int*   off   = (int*)(ws + o_off);
    float* nrm   = (float*)(ws + o_nrm);
    int*   csr   = (int*)(ws + o_csr);
    int*   stg   = (int*)(ws + o_stg);
    int*   bh    = (int*)(ws + o_bh);
    int*   bb    = (int*)(ws + o_bb);
    int*   bc    = (int*)(ws + o_bc);
    unsigned short* h1 = (unsigned short*)(ws + o_h);         // [Nn,64] bf16
    float*          q  = (float*)(ws + o_h);                  // [Nn,64] f32, h1 dead by then
    unsigned short* p  = (unsigned short*)(out + (size_t)Nn * F_HID); // bf16, upper half of d_out

    // ---- CSR build, both phases hidden under gemm1 halves ----
    hipMemsetAsync(ws + o_bh, 0, 3 * MAXNB * 4, stream);   // bh+bb+bc
    bhist_kernel<<<512, 256, 0, stream>>>(dst, bh, E, Nn, NB);
    int G1  = (Nn + 127) / 128;                 // 782 gemm1 blocks total (RB=128)
    int G1A = G1 / 2;                           // rows [0, G1A*128)   -> K1
    int G1B = G1 - G1A;                         // rows [G1A*128, ...) -> K2
    gemm1a_bplace_kernel<<<G1A + 256, 256, 0, stream>>>(
        x, W1, h1, Nn, G1A,
        src, dst, bh, bb, bc, stg, E, Nn, NB, 256);
    gemm1b_bfine_kernel<<<G1B + NB, 256, 0, stream>>>(
        x, W1, h1, Nn, G1A, G1B,
        bh, bb, stg, cnt, off, nrm, csr, Nn);

    // ---- layer 1 gather: p = bf16(nv*relu(nv*(sum norm[s]*h1[s] + nv*h1) + b1)) ----
    gather64_conv_kernel<<<(Nn + 3) / 4, 256, 0, stream>>>(
        h1, nrm, off, cnt, csr, b1, p, Nn, E);

    // ---- layer 2: q = nv*(sum_p+p) ; out = q@W2 + b2 ----
    gather64_plain_kernel<<<(Nn + 3) / 4, 256, 0, stream>>>(
        p, nrm, off, cnt, csr, q, Nn, E);
    {
        constexpr int RB = (256 / (F_OUT / 8)) * 4;  // 64 rows/block -> 1563 blocks
        gemm_tiled<F_HID, F_OUT, true, false><<<(Nn + RB - 1) / RB, 256, 0, stream>>>(
            q, W2, b2, out, Nn);
    }
}

// Round 15
// 315.869 us; speedup vs baseline: 1.1206x; 1.1206x over previous
//
#include <hip/hip_runtime.h>
#include <hip/hip_bf16.h>

#define F_IN 128
#define F_HID 64
#define F_OUT 128
#define BSH 9                 // 512 nodes per bucket
#define BS  (1 << BSH)
#define MAXNB 256

__device__ __forceinline__ int clampi(int v, int lo, int hi) {
    return v < lo ? lo : (v > hi ? hi : v);
}

// RNE float->bf16 (explicit, no dependence on hip_bf16 ABI)
__device__ __forceinline__ unsigned short f2bf(float f) {
    unsigned int u = __float_as_uint(f);
    u = (u + 0x7FFFu + ((u >> 16) & 1u)) >> 16;
    return (unsigned short)u;
}
__device__ __forceinline__ float bf2f(unsigned short s) {
    return __uint_as_float(((unsigned int)s) << 16);
}

// ---------------- B1: coarse bucket histogram ----------------
__global__ void bhist_kernel(const int* __restrict__ dst, int* __restrict__ bhist,
                             int E, int Nn, int NB) {
    __shared__ int lh[MAXNB];
    for (int i = threadIdx.x; i < NB; i += 256) lh[i] = 0;
    __syncthreads();
    int chunk = (E + gridDim.x - 1) / gridDim.x;
    int base = blockIdx.x * chunk;
    int end = base + chunk; if (end > E) end = E;
    for (int i = base + threadIdx.x; i < end; i += 256) {
        int d = clampi(dst[i], 0, Nn - 1);
        atomicAdd(&lh[d >> BSH], 1);
    }
    __syncthreads();
    for (int i = threadIdx.x; i < NB; i += 256)
        if (lh[i]) atomicAdd(&bhist[i], lh[i]);
}

// ---------------- bplace BODY (device fn; LDS passed in; r7-r13 proven) ----------------
__device__ void bplace_body(int* lh, int* gb, int* bbuf, int lb, int NPL,
                            const int* __restrict__ src, const int* __restrict__ dst,
                            const int* __restrict__ bhist, int* __restrict__ bbase,
                            int* __restrict__ bcur, int* __restrict__ staging,
                            int E, int Nn, int NB) {
    int t = threadIdx.x;                         // blockDim = 256 = MAXNB
    int v = (t < NB) ? bhist[t] : 0;
    bbuf[t] = v;
    __syncthreads();
    for (int dd = 1; dd < MAXNB; dd <<= 1) {
        int x = (t >= dd) ? bbuf[t - dd] : 0;
        __syncthreads();
        bbuf[t] += x;
        __syncthreads();
    }
    int excl = bbuf[t] - v;
    __syncthreads();
    bbuf[t] = excl;
    if (lb == 0 && t < NB) bbase[t] = excl;
    for (int i = t; i < NB; i += 256) lh[i] = 0;
    __syncthreads();

    int chunk = (E + NPL - 1) / NPL;
    int base = lb * chunk;
    int end = base + chunk; if (end > E) end = E;
    for (int i = base + t; i < end; i += 256) {
        int d = clampi(dst[i], 0, Nn - 1);
        atomicAdd(&lh[d >> BSH], 1);
    }
    __syncthreads();
    for (int i = t; i < NB; i += 256) {
        int c = lh[i];
        gb[i] = (c > 0) ? bbuf[i] + atomicAdd(&bcur[i], c) : 0;
        lh[i] = 0;                               // reuse as local cursor
    }
    __syncthreads();
    for (int i = base + t; i < end; i += 256) {
        int d = clampi(dst[i], 0, Nn - 1);
        int s = clampi(src[i], 0, Nn - 1);
        int b = d >> BSH;
        int p = gb[b] + atomicAdd(&lh[b], 1);    // contiguous run per block*bucket
        staging[p] = (s << BSH) | (d & (BS - 1));
    }
}

// ---------------- C: per-bucket fine fill -> cnt/off/norm/csr (1024 thr) ----------------
// STANDALONE by design. r14 lesson: splitting gemm1 in half to hide bfine
// under the second half REGRESSED (318->354): a latency-bound gemm kernel has
// a ~55-60us floor regardless of half/full grid (time = per-block latency
// chain x occupancy rounds + ramp), so two sequential halves pay the floor
// twice. The r9 fusion only pays when filler rides along a FULL-size gemm.
__global__ void bfine_kernel(const int* __restrict__ bhist, const int* __restrict__ bbase,
                             const int* __restrict__ staging,
                             int* __restrict__ cnt, int* __restrict__ off,
                             float* __restrict__ nrm, int* __restrict__ csr, int Nn) {
    __shared__ int lcnt[BS];
    __shared__ int loff[BS];
    __shared__ int lcur[BS];
    int b = blockIdx.x;
    int t = threadIdx.x;                         // blockDim = 1024
    int base  = bbase[b];
    int count = bhist[b];
    int node0 = b << BSH;

    if (t < BS) lcnt[t] = 0;
    __syncthreads();
    for (int i = t; i < count; i += 1024)
        atomicAdd(&lcnt[staging[base + i] & (BS - 1)], 1);
    __syncthreads();

    int myv = 0;
    if (t < BS) { myv = lcnt[t]; loff[t] = myv; }
    __syncthreads();
    for (int d = 1; d < BS; d <<= 1) {
        int x = 0;
        if (t < BS && t >= d) x = loff[t - d];
        __syncthreads();
        if (t < BS) loff[t] += x;
        __syncthreads();
    }
    if (t < BS) loff[t] -= myv;                  // inclusive -> exclusive
    __syncthreads();

    if (t < BS) {
        int node = node0 + t;
        if (node < Nn) {
            int c = lcnt[t];
            cnt[node] = c;
            off[node] = base + loff[t];
            nrm[node] = rsqrtf((float)c + 1.0f);
        }
        lcur[t] = 0;
    }
    __syncthreads();

    for (int i = t; i < count; i += 1024) {
        int v = staging[base + i];
        int r = v & (BS - 1);
        int p = base + loff[r] + atomicAdd(&lcur[r], 1);
        csr[p] = v >> BSH;
    }
}

// ---------------- GEMM BODY (v5 straight kk+=8 loop — PERMANENTLY FROZEN) ----------------
// r12 verdict: ping-pong prefetch state (acc 32 + 64 prefetch VGPR > budget)
// deterministically spills -> GB-scale scratch storm (FETCH~=WRITE~=2GB,
// VALUBusy 1.3%, 1.64ms — identical across sessions). This body (peak live
// ~70, av/av2 die between j-loops) ran clean r4/r8/r9/r10/r13. DO NOT ADD
// PREFETCH STATE. DO NOT CHANGE GEOMETRY. DO NOT SPLIT THE GRID (r14).
template<int K, int N, bool BIAS, bool BF16OUT>
__device__ void gemm_body(float* __restrict__ Ws, int lb,
                          const float* __restrict__ A, const float* __restrict__ B,
                          const float* __restrict__ bias,
                          void* __restrict__ Cv, int M) {
    constexpr int CT = N / 8;
    constexpr int RB = (256 / CT) * 4;

    int tid = threadIdx.x;
    for (int i = tid; i < K * N / 4; i += 256)
        ((float4*)Ws)[i] = ((const float4*)B)[i];
    __syncthreads();

    int ct = tid % CT;
    int rt = tid / CT;
    int row0 = lb * RB + rt * 4;
    int c0 = ct * 8;

    float acc[4][8];
#pragma unroll
    for (int r = 0; r < 4; r++)
#pragma unroll
        for (int c = 0; c < 8; c++) acc[r][c] = 0.f;

    for (int kk = 0; kk < K; kk += 8) {
        float4 av[4], av2[4];
#pragma unroll
        for (int r = 0; r < 4; r++) {
            int row = row0 + r;
            if (row < M) {
                av[r]  = *(const float4*)(A + (size_t)row * K + kk);
                av2[r] = *(const float4*)(A + (size_t)row * K + kk + 4);
            } else {
                av[r]  = make_float4(0.f, 0.f, 0.f, 0.f);
                av2[r] = make_float4(0.f, 0.f, 0.f, 0.f);
            }
        }
#pragma unroll
        for (int j = 0; j < 4; j++) {
            const float* wrow = Ws + (kk + j) * N + c0;
            float4 w0 = *(const float4*)(wrow);
            float4 w1 = *(const float4*)(wrow + 4);
            float wj[8] = {w0.x, w0.y, w0.z, w0.w, w1.x, w1.y, w1.z, w1.w};
#pragma unroll
            for (int r = 0; r < 4; r++) {
                float a = (j == 0) ? av[r].x : (j == 1) ? av[r].y : (j == 2) ? av[r].z : av[r].w;
#pragma unroll
                for (int c = 0; c < 8; c++)
                    acc[r][c] = fmaf(a, wj[c], acc[r][c]);
            }
        }
#pragma unroll
        for (int j = 0; j < 4; j++) {
            const float* wrow = Ws + (kk + 4 + j) * N + c0;
            float4 w0 = *(const float4*)(wrow);
            float4 w1 = *(const float4*)(wrow + 4);
            float wj[8] = {w0.x, w0.y, w0.z, w0.w, w1.x, w1.y, w1.z, w1.w};
#pragma unroll
            for (int r = 0; r < 4; r++) {
                float a = (j == 0) ? av2[r].x : (j == 1) ? av2[r].y : (j == 2) ? av2[r].z : av2[r].w;
#pragma unroll
                for (int c = 0; c < 8; c++)
                    acc[r][c] = fmaf(a, wj[c], acc[r][c]);
            }
        }
    }

    float bcol[8];
    if (BIAS) {
        float4 bb0 = *(const float4*)(bias + c0);
        float4 bb1 = *(const float4*)(bias + c0 + 4);
        bcol[0]=bb0.x; bcol[1]=bb0.y; bcol[2]=bb0.z; bcol[3]=bb0.w;
        bcol[4]=bb1.x; bcol[5]=bb1.y; bcol[6]=bb1.z; bcol[7]=bb1.w;
    }

#pragma unroll
    for (int r = 0; r < 4; r++) {
        int row = row0 + r;
        if (row >= M) continue;
        float o[8];
#pragma unroll
        for (int c = 0; c < 8; c++) {
            float v = acc[r][c];
            if (BIAS) v += bcol[c];
            o[c] = v;
        }
        if (BF16OUT) {
            unsigned int pk0 = (unsigned int)f2bf(o[0]) | ((unsigned int)f2bf(o[1]) << 16);
            unsigned int pk1 = (unsigned int)f2bf(o[2]) | ((unsigned int)f2bf(o[3]) << 16);
            unsigned int pk2 = (unsigned int)f2bf(o[4]) | ((unsigned int)f2bf(o[5]) << 16);
            unsigned int pk3 = (unsigned int)f2bf(o[6]) | ((unsigned int)f2bf(o[7]) << 16);
            uint4 pk; pk.x = pk0; pk.y = pk1; pk.z = pk2; pk.w = pk3;
            *(uint4*)((unsigned short*)Cv + (size_t)row * N + c0) = pk;
        } else {
            float4 o0, o1;
            o0.x = o[0]; o0.y = o[1]; o0.z = o[2]; o0.w = o[3];
            o1.x = o[4]; o1.y = o[5]; o1.z = o[6]; o1.w = o[7];
            float* crow = (float*)Cv + (size_t)row * N + c0;
            *(float4*)(crow) = o0;
            *(float4*)(crow + 4) = o1;
        }
    }
}

// ---------------- standalone GEMM kernel (layer 2) ----------------
template<int K, int N, bool BIAS, bool BF16OUT>
__global__ void gemm_tiled(const float* __restrict__ A, const float* __restrict__ B,
                           const float* __restrict__ bias,
                           void* __restrict__ Cv, int M) {
    __shared__ float Ws[K * N];
    gemm_body<K, N, BIAS, BF16OUT>(Ws, blockIdx.x, A, B, bias, Cv, M);
}

// ---------------- FUSED: gemm1 (full grid) || bplace (CSR) ----------------
// r9/r10/r13 verified: bplace (~15-20us serial) hides inside the FULL-size
// gemm1's latency stalls at ~3us marginal cost. Keep the gemm whole (r14).
__global__ void gemm1_bplace_kernel(const float* __restrict__ x, const float* __restrict__ W1,
                                    unsigned short* __restrict__ h1, int M, int NG,
                                    const int* __restrict__ src, const int* __restrict__ dst,
                                    const int* __restrict__ bhist, int* __restrict__ bbase,
                                    int* __restrict__ bcur, int* __restrict__ staging,
                                    int E, int Nn, int NB, int NPL) {
    __shared__ union SmA {
        float ws[F_IN * F_HID];                         // 32 KB
        struct { int lh[MAXNB]; int gb[MAXNB]; int bb[MAXNB]; } pl;  // 3 KB
    } sm;
    if ((int)blockIdx.x < NG) {
        gemm_body<F_IN, F_HID, false, true>(sm.ws, blockIdx.x, x, W1, nullptr, h1, M);
    } else {
        bplace_body(sm.pl.lh, sm.pl.gb, sm.pl.bb, blockIdx.x - NG, NPL,
                    src, dst, bhist, bbase, bcur, staging, E, Nn, NB);
    }
}

// ---------------- gather1 (CONV): per-edge norm fma (h1 is UNSCALED bf16) ----------------
__global__ void gather64_conv_kernel(const unsigned short* __restrict__ h,
                                     const float* __restrict__ norm,
                                     const int* __restrict__ off, const int* __restrict__ cnt,
                                     const int* __restrict__ csr_src,
                                     const float* __restrict__ bias,
                                     unsigned short* __restrict__ outp, int Nn, int E) {
    int wave = (blockIdx.x * blockDim.x + threadIdx.x) >> 6;
    int lane = threadIdx.x & 63;
    int node = __builtin_amdgcn_readfirstlane(wave);
    if (node >= Nn) return;

    int o0 = __builtin_amdgcn_readfirstlane(off[node]);
    int c  = __builtin_amdgcn_readfirstlane(cnt[node]);
    if (c < 0) c = 0;
    if (o0 < 0) o0 = 0;
    if (o0 + c > E) c = E - o0;

    const int* ce = csr_src + o0;
    float sum = 0.0f;
    int e = 0;
    for (; e + 16 <= c; e += 16) {
        int si[16];
        float nw[16];
        unsigned short v[16];
#pragma unroll
        for (int u = 0; u < 16; u++) si[u] = clampi(ce[e + u], 0, Nn - 1);
#pragma unroll
        for (int u = 0; u < 16; u++) nw[u] = norm[si[u]];
#pragma unroll
        for (int u = 0; u < 16; u++) v[u] = h[(size_t)si[u] * 64 + lane];
#pragma unroll
        for (int u = 0; u < 16; u++) sum = fmaf(nw[u], bf2f(v[u]), sum);
    }
    for (; e + 8 <= c; e += 8) {
        int si[8];
        float nw[8];
        unsigned short v[8];
#pragma unroll
        for (int u = 0; u < 8; u++) si[u] = clampi(ce[e + u], 0, Nn - 1);
#pragma unroll
        for (int u = 0; u < 8; u++) nw[u] = norm[si[u]];
#pragma unroll
        for (int u = 0; u < 8; u++) v[u] = h[(size_t)si[u] * 64 + lane];
#pragma unroll
        for (int u = 0; u < 8; u++) sum = fmaf(nw[u], bf2f(v[u]), sum);
    }
    for (; e + 4 <= c; e += 4) {
        int si[4];
        float nw[4];
        unsigned short v[4];
#pragma unroll
        for (int u = 0; u < 4; u++) si[u] = clampi(ce[e + u], 0, Nn - 1);
#pragma unroll
        for (int u = 0; u < 4; u++) nw[u] = norm[si[u]];
#pragma unroll
        for (int u = 0; u < 4; u++) v[u] = h[(size_t)si[u] * 64 + lane];
#pragma unroll
        for (int u = 0; u < 4; u++) sum = fmaf(nw[u], bf2f(v[u]), sum);
    }
    for (; e < c; e++) {
        int s = clampi(ce[e], 0, Nn - 1);
        sum = fmaf(norm[s], bf2f(h[(size_t)s * 64 + lane]), sum);
    }
    float self = bf2f(h[(size_t)node * 64 + lane]);
    float nv = norm[node];
    float r = nv * (sum + nv * self);
    r = nv * fmaxf(r + bias[lane], 0.0f);
    outp[(size_t)node * 64 + lane] = f2bf(r);
}

// ---------------- gather2 (plain): p is pre-scaled bf16; q = nv*(sum+self) f32 ----------------
__global__ void gather64_plain_kernel(const unsigned short* __restrict__ h,
                                      const float* __restrict__ norm,
                                      const int* __restrict__ off, const int* __restrict__ cnt,
                                      const int* __restrict__ csr_src,
                                      float* __restrict__ outq, int Nn, int E) {
    int wave = (blockIdx.x * blockDim.x + threadIdx.x) >> 6;
    int lane = threadIdx.x & 63;
    int node = __builtin_amdgcn_readfirstlane(wave);
    if (node >= Nn) return;

    int o0 = __builtin_amdgcn_readfirstlane(off[node]);
    int c  = __builtin_amdgcn_readfirstlane(cnt[node]);
    if (c < 0) c = 0;
    if (o0 < 0) o0 = 0;
    if (o0 + c > E) c = E - o0;

    const int* ce = csr_src + o0;
    float sum = 0.0f;
    int e = 0;
    for (; e + 16 <= c; e += 16) {
        int si[16];
        unsigned short v[16];
#pragma unroll
        for (int u = 0; u < 16; u++) si[u] = clampi(ce[e + u], 0, Nn - 1);
#pragma unroll
        for (int u = 0; u < 16; u++) v[u] = h[(size_t)si[u] * 64 + lane];
#pragma unroll
        for (int u = 0; u < 16; u++) sum += bf2f(v[u]);
    }
    for (; e + 8 <= c; e += 8) {
        int si[8];
        unsigned short v[8];
#pragma unroll
        for (int u = 0; u < 8; u++) si[u] = clampi(ce[e + u], 0, Nn - 1);
#pragma unroll
        for (int u = 0; u < 8; u++) v[u] = h[(size_t)si[u] * 64 + lane];
#pragma unroll
        for (int u = 0; u < 8; u++) sum += bf2f(v[u]);
    }
    for (; e + 4 <= c; e += 4) {
        int si[4];
        unsigned short v[4];
#pragma unroll
        for (int u = 0; u < 4; u++) si[u] = clampi(ce[e + u], 0, Nn - 1);
#pragma unroll
        for (int u = 0; u < 4; u++) v[u] = h[(size_t)si[u] * 64 + lane];
#pragma unroll
        for (int u = 0; u < 4; u++) sum += bf2f(v[u]);
    }
    for (; e < c; e++) {
        int s = clampi(ce[e], 0, Nn - 1);
        sum += bf2f(h[(size_t)s * 64 + lane]);
    }
    float self = bf2f(h[(size_t)node * 64 + lane]);
    float nv = norm[node];
    outq[(size_t)node * 64 + lane] = nv * (sum + self);
}

extern "C" void kernel_launch(void* const* d_in, const int* in_sizes, int n_in,
                              void* d_out, int out_size, void* d_ws, size_t ws_size,
                              hipStream_t stream) {
    if (n_in < 6) return;
    const float* x   = (const float*)d_in[0];   // [N,128] f32
    const int*   ei  = (const int*)d_in[1];     // [2,E] int32
    const float* W1  = (const float*)d_in[2];   // [128,64] f32
    const float* b1  = (const float*)d_in[3];   // [64] f32
    const float* W2  = (const float*)d_in[4];   // [64,128] f32
    const float* b2  = (const float*)d_in[5];   // [128] f32
    float*       out = (float*)d_out;           // [N,128] f32

    int Nn = in_sizes[0] / F_IN;
    int E  = in_sizes[1] / 2;
    const int* src = ei;
    const int* dst = ei + E;

    int NB = (Nn + BS - 1) >> BSH;              // 196 for 100k
    if (NB > MAXNB) return;
    if (Nn > (1 << (31 - BSH))) return;

    // ---- workspace layout (~40 MB), guarded ----
    size_t o = 0;
    auto alloc = [&](size_t bytes) { size_t cur = o; o += (bytes + 255) & ~(size_t)255; return cur; };
    size_t o_cnt   = alloc((size_t)Nn * 4);
    size_t o_off   = alloc((size_t)Nn * 4);
    size_t o_nrm   = alloc((size_t)Nn * 4);
    size_t o_csr   = alloc((size_t)E * 4);
    size_t o_stg   = alloc((size_t)E * 4);
    size_t o_bh    = alloc(MAXNB * 4);          // bh, bb, bc contiguous (3 KB)
    size_t o_bb    = alloc(MAXNB * 4);
    size_t o_bc    = alloc(MAXNB * 4);
    size_t o_h     = alloc((size_t)Nn * F_HID * 4);   // q (f32) overlays h1 (bf16)
    if (o > ws_size) return;

    char* ws = (char*)d_ws;
    int*   cnt   = (int*)(ws + o_cnt);
    int*   off   = (int*)(ws + o_off);
    float* nrm   = (float*)(ws + o_nrm);
    int*   csr   = (int*)(ws + o_csr);
    int*   stg   = (int*)(ws + o_stg);
    int*   bh    = (int*)(ws + o_bh);
    int*   bb    = (int*)(ws + o_bb);
    int*   bc    = (int*)(ws + o_bc);
    unsigned short* h1 = (unsigned short*)(ws + o_h);         // [Nn,64] bf16
    float*          q  = (float*)(ws + o_h);                  // [Nn,64] f32, h1 dead by then
    unsigned short* p  = (unsigned short*)(out + (size_t)Nn * F_HID); // bf16, upper half of d_out

    // ---- CSR build, with gemm1 fused alongside bplace (r13 config, 317.8us) ----
    hipMemsetAsync(ws + o_bh, 0, 3 * MAXNB * 4, stream);   // bh+bb+bc
    bhist_kernel<<<512, 256, 0, stream>>>(dst, bh, E, Nn, NB);
    int G1 = (Nn + 127) / 128;                  // 782 gemm1 blocks (RB=128)
    gemm1_bplace_kernel<<<G1 + 256, 256, 0, stream>>>(
        x, W1, h1, Nn, G1,
        src, dst, bh, bb, bc, stg, E, Nn, NB, 256);
    bfine_kernel<<<NB, 1024, 0, stream>>>(bh, bb, stg, cnt, off, nrm, csr, Nn);

    // ---- layer 1 gather: p = bf16(nv*relu(nv*(sum norm[s]*h1[s] + nv*h1) + b1)) ----
    gather64_conv_kernel<<<(Nn + 3) / 4, 256, 0, stream>>>(
        h1, nrm, off, cnt, csr, b1, p, Nn, E);

    // ---- layer 2: q = nv*(sum_p+p) ; out = q@W2 + b2 ----
    gather64_plain_kernel<<<(Nn + 3) / 4, 256, 0, stream>>>(
        p, nrm, off, cnt, csr, q, Nn, E);
    {
        constexpr int RB = (256 / (F_OUT / 8)) * 4;  // 64 rows/block -> 1563 blocks
        gemm_tiled<F_HID, F_OUT, true, false><<<(Nn + RB - 1) / RB, 256, 0, stream>>>(
            q, W2, b2, out, Nn);
    }
}